// Round 5
// baseline (276.261 us; speedup 1.0000x reference)
//
#include <hip/hip_runtime.h>
#include <hip/hip_bf16.h>

// GraphSAGE forward:
//   CSR build (ILP-8 count/fill) -> wconv -> linear1 (MFMA) ->
//   3x [agg gather-mean bf16 + MFMA GEMM(norm,relu)] -> linear2
// h/agg stored bf16; GEMMs via mfma_f32_16x16x32_bf16 (f32 accumulate); no LDS in GEMM.

#define NT 256
#define EILP 8

typedef __attribute__((ext_vector_type(8))) short bf16x8;
typedef __attribute__((ext_vector_type(4))) float f32x4;

__device__ __forceinline__ float bfbits2f(unsigned short b) {
    return __uint_as_float(((unsigned)b) << 16);
}
__device__ __forceinline__ unsigned short f2bfbits(float v) {
    __hip_bfloat16 b = __float2bfloat16(v);
    return *reinterpret_cast<unsigned short*>(&b);
}

// ---------------- CSR build ----------------

// 8 edges per thread: 8 independent atomic round-trips in flight per lane.
__global__ void count_kernel(const int* __restrict__ dst, int* __restrict__ cnt,
                             int* __restrict__ rank, int m) {
    const int base = blockIdx.x * (NT * EILP) + threadIdx.x;
    int d[EILP], r[EILP];
    #pragma unroll
    for (int p = 0; p < EILP; ++p) {
        const int e = base + p * NT;
        d[p] = (e < m) ? dst[e] : -1;
    }
    #pragma unroll
    for (int p = 0; p < EILP; ++p)
        if (d[p] >= 0) r[p] = atomicAdd(&cnt[d[p]], 1);
    #pragma unroll
    for (int p = 0; p < EILP; ++p) {
        const int e = base + p * NT;
        if (e < m) rank[e] = r[p];
    }
}

__global__ void reduce_chunk_kernel(const int* __restrict__ cnt, int* __restrict__ bsum, int n) {
    __shared__ int ws[4];
    const int t = threadIdx.x, lane = t & 63, wid = t >> 6;
    const int base = blockIdx.x * 1024;
    int s = 0;
    #pragma unroll
    for (int p = 0; p < 4; ++p) {
        const int idx = base + p * 256 + t;
        s += (idx < n) ? cnt[idx] : 0;
    }
    #pragma unroll
    for (int off = 32; off > 0; off >>= 1) s += __shfl_xor(s, off, 64);
    if (lane == 0) ws[wid] = s;
    __syncthreads();
    if (t == 0) bsum[blockIdx.x] = ws[0] + ws[1] + ws[2] + ws[3];
}

__global__ void scan_bsums_kernel(const int* __restrict__ bsum, int* __restrict__ bexcl,
                                  int* __restrict__ row_ptr, int n, int nb) {
    __shared__ int w0;
    const int t = threadIdx.x, lane = t & 63, wid = t >> 6;
    const int v = (t < nb) ? bsum[t] : 0;
    int x = v;
    #pragma unroll
    for (int off = 1; off < 64; off <<= 1) {
        const int tt = __shfl_up(x, off, 64);
        if (lane >= off) x += tt;
    }
    if (wid == 0 && lane == 63) w0 = x;
    __syncthreads();
    const int incl = x + (wid ? w0 : 0);
    if (t < nb) bexcl[t] = incl - v;
    if (t == nb - 1) row_ptr[n] = incl;
}

__global__ void scan_apply_kernel(const int* __restrict__ cnt, const int* __restrict__ bexcl,
                                  int* __restrict__ row_ptr, int n) {
    __shared__ int wsum[4];
    const int t = threadIdx.x, lane = t & 63, wid = t >> 6;
    const int base = blockIdx.x * 1024 + t * 4;
    int4 v = make_int4(0, 0, 0, 0);
    if (base + 3 < n) v = *(const int4*)&cnt[base];
    else {
        if (base < n)     v.x = cnt[base];
        if (base + 1 < n) v.y = cnt[base + 1];
        if (base + 2 < n) v.z = cnt[base + 2];
    }
    const int tsum = v.x + v.y + v.z + v.w;
    int x = tsum;
    #pragma unroll
    for (int off = 1; off < 64; off <<= 1) {
        const int tt = __shfl_up(x, off, 64);
        if (lane >= off) x += tt;
    }
    if (lane == 63) wsum[wid] = x;
    __syncthreads();
    int woff = 0;
    for (int w = 0; w < wid; ++w) woff += wsum[w];
    int e = bexcl[blockIdx.x] + woff + (x - tsum);
    int4 o;
    o.x = e; o.y = e + v.x; o.z = o.y + v.y; o.w = o.z + v.z;
    if (base + 3 < n) *(int4*)&row_ptr[base] = o;
    else {
        if (base < n)     row_ptr[base]     = o.x;
        if (base + 1 < n) row_ptr[base + 1] = o.y;
        if (base + 2 < n) row_ptr[base + 2] = o.z;
    }
}

// 8 edges per thread: 8 independent row_ptr gathers + scatter stores in flight.
__global__ void fill_kernel(const int* __restrict__ src, const int* __restrict__ dst,
                            const int* __restrict__ row_ptr, const int* __restrict__ rank,
                            int* __restrict__ csr, int m) {
    const int base = blockIdx.x * (NT * EILP) + threadIdx.x;
    int d[EILP], s[EILP], rk[EILP], rp[EILP];
    #pragma unroll
    for (int p = 0; p < EILP; ++p) {
        const int e = base + p * NT;
        if (e < m) { d[p] = dst[e]; s[p] = src[e]; rk[p] = rank[e]; }
        else d[p] = -1;
    }
    #pragma unroll
    for (int p = 0; p < EILP; ++p)
        if (d[p] >= 0) rp[p] = row_ptr[d[p]];
    #pragma unroll
    for (int p = 0; p < EILP; ++p)
        if (d[p] >= 0) csr[rp[p] + rk[p]] = s[p];
}

// ---------------- weight convert+transpose: Wt[col][k] bf16 ----------------

__global__ void wconv_kernel(const float* __restrict__ W1, const float* __restrict__ Wl,
                             const float* __restrict__ Wr, const float* __restrict__ W2,
                             unsigned short* __restrict__ out) {
    int i = blockIdx.x * blockDim.x + threadIdx.x;
    if (i >= 36864) return;
    float v;
    if (i < 8192) {
        const int col = i >> 7, k = i & 127;
        v = W1[k * 64 + col];
    } else if (i < 32768) {
        const int j = i - 8192;
        const int mm = j >> 13, r = j & 8191;
        const int isR = (r >> 12) & 1, q = r & 4095;
        const int col = q >> 6, k = q & 63;
        v = (isR ? Wr : Wl)[mm * 4096 + k * 64 + col];
    } else {
        const int q = i - 32768;
        const int col = q >> 6, k = q & 63;
        v = W2[k * 64 + col];
    }
    out[i] = f2bfbits(v);
}

// ---------------- aggregation: aggB[node] = bf16(mean over in-edges of h[src]) ----------------
// lane split: g=lane>>4 (edge slot), c=lane&15 (4 cols each). 4 edges per wave-load.

__global__ __launch_bounds__(NT) void agg_kernel(const unsigned short* __restrict__ h,
    const int* __restrict__ row_ptr, const int* __restrict__ csr,
    unsigned short* __restrict__ aggB, int n) {
    const int t = threadIdx.x;
    const int lane = t & 63;
    const int g = lane >> 4;
    const int c = lane & 15;
    const int gw = (blockIdx.x * NT + t) >> 6;
    const int nw = (gridDim.x * NT) >> 6;
    for (int node = gw; node < n; node += nw) {
        const int rs = row_ptr[node];
        const int re = row_ptr[node + 1];
        float a0 = 0.f, a1 = 0.f, a2 = 0.f, a3 = 0.f;
        int e = rs;
        for (; e + 16 <= re; e += 16) {
            const int s0 = csr[e + g];
            const int s1 = csr[e + 4 + g];
            const int s2 = csr[e + 8 + g];
            const int s3 = csr[e + 12 + g];
            const ushort4 v0 = *(const ushort4*)&h[(size_t)s0 * 64 + c * 4];
            const ushort4 v1 = *(const ushort4*)&h[(size_t)s1 * 64 + c * 4];
            const ushort4 v2 = *(const ushort4*)&h[(size_t)s2 * 64 + c * 4];
            const ushort4 v3 = *(const ushort4*)&h[(size_t)s3 * 64 + c * 4];
            a0 += (bfbits2f(v0.x) + bfbits2f(v1.x)) + (bfbits2f(v2.x) + bfbits2f(v3.x));
            a1 += (bfbits2f(v0.y) + bfbits2f(v1.y)) + (bfbits2f(v2.y) + bfbits2f(v3.y));
            a2 += (bfbits2f(v0.z) + bfbits2f(v1.z)) + (bfbits2f(v2.z) + bfbits2f(v3.z));
            a3 += (bfbits2f(v0.w) + bfbits2f(v1.w)) + (bfbits2f(v2.w) + bfbits2f(v3.w));
        }
        for (; e + 8 <= re; e += 8) {
            const int s0 = csr[e + g];
            const int s1 = csr[e + 4 + g];
            const ushort4 v0 = *(const ushort4*)&h[(size_t)s0 * 64 + c * 4];
            const ushort4 v1 = *(const ushort4*)&h[(size_t)s1 * 64 + c * 4];
            a0 += bfbits2f(v0.x) + bfbits2f(v1.x);
            a1 += bfbits2f(v0.y) + bfbits2f(v1.y);
            a2 += bfbits2f(v0.z) + bfbits2f(v1.z);
            a3 += bfbits2f(v0.w) + bfbits2f(v1.w);
        }
        for (; e + 4 <= re; e += 4) {
            const int s0 = csr[e + g];
            const ushort4 v0 = *(const ushort4*)&h[(size_t)s0 * 64 + c * 4];
            a0 += bfbits2f(v0.x);
            a1 += bfbits2f(v0.y);
            a2 += bfbits2f(v0.z);
            a3 += bfbits2f(v0.w);
        }
        const int r = re - e;
        if (g < r) {
            const int s0 = csr[e + g];
            const ushort4 v0 = *(const ushort4*)&h[(size_t)s0 * 64 + c * 4];
            a0 += bfbits2f(v0.x);
            a1 += bfbits2f(v0.y);
            a2 += bfbits2f(v0.z);
            a3 += bfbits2f(v0.w);
        }
        a0 += __shfl_xor(a0, 16, 64); a0 += __shfl_xor(a0, 32, 64);
        a1 += __shfl_xor(a1, 16, 64); a1 += __shfl_xor(a1, 32, 64);
        a2 += __shfl_xor(a2, 16, 64); a2 += __shfl_xor(a2, 32, 64);
        a3 += __shfl_xor(a3, 16, 64); a3 += __shfl_xor(a3, 32, 64);
        if (g == 0) {
            const float inv = (re > rs) ? (1.0f / (float)(re - rs)) : 0.0f;
            ushort4 o;
            o.x = f2bfbits(a0 * inv);
            o.y = f2bfbits(a1 * inv);
            o.z = f2bfbits(a2 * inv);
            o.w = f2bfbits(a3 * inv);
            *(ushort4*)&aggB[(size_t)node * 64 + c * 4] = o;
        }
    }
}

// ---------------- MFMA GEMM: C[n,64] = A1@W1 [+ A2@W2] + bias; optional L2norm+relu ----------------
// block = 4 waves, wave = 32 rows x 64 cols (2 row-tiles x 4 col-tiles of 16x16x32 mfma).
// C/D: col = lane&15, row = (lane>>4)*4 + reg.

template<int A1F32>
__global__ __launch_bounds__(NT) void gemm_mfma(
    const float* __restrict__ A1f, const unsigned short* __restrict__ A1b,
    int ldA1, int K1, const unsigned short* __restrict__ W1t,
    const unsigned short* __restrict__ A2b, const unsigned short* __restrict__ W2t,
    const float* __restrict__ bias, float* __restrict__ outF,
    unsigned short* __restrict__ outB, int n, int do_norm) {
    const int t = threadIdx.x;
    const int lane = t & 63;
    const int w = t >> 6;
    const int r16 = lane & 15;
    const int g = lane >> 4;
    const int row0 = blockIdx.x * 128 + w * 32;

    f32x4 acc[2][4];
    #pragma unroll
    for (int i = 0; i < 2; ++i)
        #pragma unroll
        for (int j = 0; j < 4; ++j) {
            acc[i][j][0] = 0.f; acc[i][j][1] = 0.f; acc[i][j][2] = 0.f; acc[i][j][3] = 0.f;
        }

    int ra[2];
    #pragma unroll
    for (int rt = 0; rt < 2; ++rt) {
        int r = row0 + rt * 16 + r16;
        ra[rt] = (r < n) ? r : (n - 1);
    }

    #pragma unroll 1
    for (int kc = 0; kc < K1; kc += 32) {
        bf16x8 af[2];
        #pragma unroll
        for (int rt = 0; rt < 2; ++rt) {
            if (A1F32) {
                const float* p = &A1f[(size_t)ra[rt] * ldA1 + kc + g * 8];
                const float4 f0 = *(const float4*)p;
                const float4 f1 = *(const float4*)(p + 4);
                bf16x8 a;
                a[0] = (short)f2bfbits(f0.x); a[1] = (short)f2bfbits(f0.y);
                a[2] = (short)f2bfbits(f0.z); a[3] = (short)f2bfbits(f0.w);
                a[4] = (short)f2bfbits(f1.x); a[5] = (short)f2bfbits(f1.y);
                a[6] = (short)f2bfbits(f1.z); a[7] = (short)f2bfbits(f1.w);
                af[rt] = a;
            } else {
                af[rt] = *(const bf16x8*)&A1b[(size_t)ra[rt] * ldA1 + kc + g * 8];
            }
        }
        #pragma unroll
        for (int ct = 0; ct < 4; ++ct) {
            const bf16x8 bw = *(const bf16x8*)&W1t[(size_t)(ct * 16 + r16) * K1 + kc + g * 8];
            acc[0][ct] = __builtin_amdgcn_mfma_f32_16x16x32_bf16(af[0], bw, acc[0][ct], 0, 0, 0);
            acc[1][ct] = __builtin_amdgcn_mfma_f32_16x16x32_bf16(af[1], bw, acc[1][ct], 0, 0, 0);
        }
    }
    if (A2b) {
        #pragma unroll 1
        for (int kc = 0; kc < 64; kc += 32) {
            bf16x8 af[2];
            #pragma unroll
            for (int rt = 0; rt < 2; ++rt)
                af[rt] = *(const bf16x8*)&A2b[(size_t)ra[rt] * 64 + kc + g * 8];
            #pragma unroll
            for (int ct = 0; ct < 4; ++ct) {
                const bf16x8 bw = *(const bf16x8*)&W2t[(size_t)(ct * 16 + r16) * 64 + kc + g * 8];
                acc[0][ct] = __builtin_amdgcn_mfma_f32_16x16x32_bf16(af[0], bw, acc[0][ct], 0, 0, 0);
                acc[1][ct] = __builtin_amdgcn_mfma_f32_16x16x32_bf16(af[1], bw, acc[1][ct], 0, 0, 0);
            }
        }
    }

    float bcol[4];
    #pragma unroll
    for (int ct = 0; ct < 4; ++ct) bcol[ct] = bias[ct * 16 + r16];

    #pragma unroll
    for (int rt = 0; rt < 2; ++rt) {
        #pragma unroll
        for (int ct = 0; ct < 4; ++ct)
            #pragma unroll
            for (int reg = 0; reg < 4; ++reg) acc[rt][ct][reg] += bcol[ct];

        if (do_norm) {
            #pragma unroll
            for (int reg = 0; reg < 4; ++reg) {
                float ss = 0.f;
                #pragma unroll
                for (int ct = 0; ct < 4; ++ct) ss += acc[rt][ct][reg] * acc[rt][ct][reg];
                ss += __shfl_xor(ss, 1, 64);
                ss += __shfl_xor(ss, 2, 64);
                ss += __shfl_xor(ss, 4, 64);
                ss += __shfl_xor(ss, 8, 64);
                const float inv = 1.0f / fmaxf(sqrtf(ss), 1e-12f);
                #pragma unroll
                for (int ct = 0; ct < 4; ++ct)
                    acc[rt][ct][reg] = fmaxf(acc[rt][ct][reg] * inv, 0.0f);
            }
        }

        const int rbase = row0 + rt * 16 + g * 4;
        #pragma unroll
        for (int reg = 0; reg < 4; ++reg) {
            const int rr = rbase + reg;
            if (rr < n) {
                if (outB) {
                    #pragma unroll
                    for (int ct = 0; ct < 4; ++ct)
                        outB[(size_t)rr * 64 + ct * 16 + r16] = f2bfbits(acc[rt][ct][reg]);
                } else {
                    #pragma unroll
                    for (int ct = 0; ct < 4; ++ct)
                        outF[(size_t)rr * 64 + ct * 16 + r16] = acc[rt][ct][reg];
                }
            }
        }
    }
}

// ---------------- launch ----------------

extern "C" void kernel_launch(void* const* d_in, const int* in_sizes, int n_in,
                              void* d_out, int out_size, void* d_ws, size_t ws_size,
                              hipStream_t stream) {
    const float* x  = (const float*)d_in[0];
    const int*   ei = (const int*)  d_in[1];
    const float* W1 = (const float*)d_in[2];
    const float* b1 = (const float*)d_in[3];
    const float* Wl = (const float*)d_in[4];
    const float* bl = (const float*)d_in[5];
    const float* Wr = (const float*)d_in[6];
    const float* W2 = (const float*)d_in[7];
    const float* b2 = (const float*)d_in[8];
    float* out = (float*)d_out;

    const int n = in_sizes[0] / 128;   // 100000
    const int m = in_sizes[1] / 2;     // 1250000
    const int* src = ei;
    const int* dst = ei + m;

    char* ws = (char*)d_ws;
    size_t off = 0;
    auto alloc = [&](size_t bytes) -> void* {
        void* p = ws + off;
        off = (off + bytes + 255) & ~(size_t)255;
        return p;
    };
    unsigned short* aggB    = (unsigned short*)alloc((size_t)n * 64 * 2);
    unsigned short* hbf     = (unsigned short*)alloc((size_t)n * 64 * 2);
    int*            row_ptr = (int*)alloc((size_t)(n + 1) * sizeof(int));
    int*            cnt     = (int*)alloc((size_t)n * sizeof(int));
    int*            bsum    = (int*)alloc(512);
    int*            bexcl   = (int*)alloc(512);
    int*            rank    = (int*)alloc((size_t)m * sizeof(int));
    int*            csr     = (int*)alloc((size_t)m * sizeof(int));
    unsigned short* wt      = (unsigned short*)alloc(36864 * 2);

    const unsigned short* W1t = wt;
    const unsigned short* W2t = wt + 32768;

    hipMemsetAsync(cnt, 0, (size_t)n * sizeof(int), stream);

    const int eb8 = (m + NT * EILP - 1) / (NT * EILP);
    const int NB = (n + 1023) / 1024;           // 98 (<=128 required by scan_bsums)
    count_kernel<<<eb8, NT, 0, stream>>>(dst, cnt, rank, m);
    reduce_chunk_kernel<<<NB, NT, 0, stream>>>(cnt, bsum, n);
    scan_bsums_kernel<<<1, 128, 0, stream>>>(bsum, bexcl, row_ptr, n, NB);
    scan_apply_kernel<<<NB, NT, 0, stream>>>(cnt, bexcl, row_ptr, n);
    fill_kernel<<<eb8, NT, 0, stream>>>(src, dst, row_ptr, rank, csr, m);
    wconv_kernel<<<144, NT, 0, stream>>>(W1, Wl, Wr, W2, wt);

    const int gtiles = (n + 127) / 128;         // 782

    // h0 = x @ W1 + b1 -> hbf (bf16)
    gemm_mfma<1><<<gtiles, NT, 0, stream>>>(x, nullptr, 128, 128, W1t,
                                            nullptr, nullptr, b1, nullptr, hbf, n, 0);

    for (int i = 0; i < 3; ++i) {
        agg_kernel<<<2048, NT, 0, stream>>>(hbf, row_ptr, csr, aggB, n);
        const unsigned short* Wlt = wt + 8192 + (size_t)i * 8192;
        const unsigned short* Wrt = Wlt + 4096;
        gemm_mfma<0><<<gtiles, NT, 0, stream>>>(nullptr, aggB, 64, 64, Wlt,
                                                hbf, Wrt, bl + (size_t)i * 64,
                                                nullptr, hbf, n, 1);
    }
    gemm_mfma<0><<<gtiles, NT, 0, stream>>>(nullptr, hbf, 64, 64, W2t,
                                            nullptr, nullptr, b2, out, nullptr, n, 0);
}